// Round 1
// 106.177 us; speedup vs baseline: 1.0069x; 1.0069x over previous
//
#include <hip/hip_runtime.h>

#define WW 128
#define HWSZ 16384
#define CC 64
#define NPLANE 512
#define NCHW 8388608      // 8*64*128*128
#define BN_EPS 1e-5f

typedef float v4f __attribute__((ext_vector_type(4)));

// ------- Kernel 1: half-plane partial sums (2 blocks per plane) -------
// XCD-consistent mapping: plane ≡ blockIdx (mod 8), so plane p's data is
// primed into XCD (p%8)'s L2.  blockIdx b: xcd=b&7, u=b>>3, j=u&63, half=u>>6,
// plane = xcd + 8*j.  (pure permutation of the old b = plane*2+half)
__global__ __launch_bounds__(256) void dc_mean_kernel(const float* __restrict__ x,
                                                      float* __restrict__ partial) {
    const int b     = blockIdx.x;                 // 0..1023
    const int xcd   = b & 7;
    const int u     = b >> 3;
    const int plane = xcd + ((u & 63) << 3);
    const int half  = u >> 6;
    const v4f* xp = (const v4f*)(x + (size_t)plane * HWSZ + half * (HWSZ / 2));
    float s = 0.f;
#pragma unroll
    for (int i = 0; i < 8; ++i) {                 // 2048 v4f / 256 thr
        v4f v = xp[threadIdx.x + i * 256];
        s += v.x + v.y + v.z + v.w;
    }
    for (int off = 32; off > 0; off >>= 1)
        s += __shfl_down(s, off, 64);
    __shared__ float wsum[4];
    if ((threadIdx.x & 63) == 0) wsum[threadIdx.x >> 6] = s;
    __syncthreads();
    if (threadIdx.x == 0)
        partial[plane * 2 + half] = wsum[0] + wsum[1] + wsum[2] + wsum[3];
}

// ---- Kernel 2: filter prologue + rolling-row dynamic 3x3 reflect conv ----
// 32 rows per block (2048 blocks); plane→XCD mapping matches kernel 1 so the
// x re-read (and inter-band halo rows) hit the local XCD's L2.
// blockIdx b: xcd=b&7, u=b>>3 (0..255), j=u&63, band=u>>6, plane = xcd + 8*j.
__global__ __launch_bounds__(256) void dc_conv_kernel(const float* __restrict__ x,
                                                      const float* __restrict__ partial,
                                                      const float* __restrict__ conv_w,
                                                      const float* __restrict__ gamma,
                                                      const float* __restrict__ beta,
                                                      const float* __restrict__ bn_mean,
                                                      const float* __restrict__ bn_var,
                                                      float* __restrict__ out) {
    const int b     = blockIdx.x;
    const int xcd   = b & 7;
    const int u     = b >> 3;
    const int plane = xcd + ((u & 63) << 3);      // n*64 + c
    const int band  = u >> 6;                     // 32-row band
    const int tid   = threadIdx.x;
    const int n = plane >> 6;
    const int c = plane & 63;

    // ---- prologue: 144-thread cooperative 9x64 dot + BN, one sync ----
    __shared__ float lv[9];
    if (tid < 144) {
        const int j    = tid >> 4;                // tap 0..8
        const int part = tid & 15;                // 16 lanes per tap, 4 channels each
        const int jj = c * 9 + j;
        v4f pa = *(const v4f*)(partial + n * 128 + part * 8);
        v4f pb = *(const v4f*)(partial + n * 128 + part * 8 + 4);
        v4f wv = *(const v4f*)(conv_w + (size_t)jj * CC + part * 4);
        float d = (pa.x + pa.y) * wv.x + (pa.z + pa.w) * wv.y
                + (pb.x + pb.y) * wv.z + (pb.z + pb.w) * wv.w;
        d += __shfl_down(d, 8, 16);
        d += __shfl_down(d, 4, 16);
        d += __shfl_down(d, 2, 16);
        d += __shfl_down(d, 1, 16);
        if (part == 0) {
            d *= (1.0f / 16384.0f);               // sum -> mean
            const float g = gamma[jj] * rsqrtf(bn_var[jj] + BN_EPS);
            lv[j] = (d - bn_mean[jj]) * g + beta[jj];
        }
    }
    __syncthreads();

    // redundant per-thread softmax from LDS broadcast
    float w9[9];
    {
        float m = lv[0];
#pragma unroll
        for (int t = 1; t < 9; ++t) m = fmaxf(m, lv[t]);
        float den = 0.f;
        float e[9];
#pragma unroll
        for (int t = 0; t < 9; ++t) { e[t] = __expf(lv[t] - m); den += e[t]; }
        const float inv = 1.0f / den;
#pragma unroll
        for (int t = 0; t < 9; ++t) w9[t] = e[t] * inv;
    }

    // ---- rolling-row conv: thread owns rows r0..r0+3, cols w0..w0+3 ----
    const int g  = tid >> 5;                      // row group 0..7 (4 rows each)
    const int q  = tid & 31;
    const int w0 = q * 4;
    const int r0 = band * 32 + g * 4;
    const float* xpl = x + (size_t)plane * HWSZ;

    v4f cP, cC, cN, cX;
    float eP0, eP1, eC0, eC1, eN0, eN1, eX0, eX1;

#define LOADROW(R, c4, e0, e1)                                              \
    {                                                                       \
        int RR = ((R) < 0) ? 1 : (((R) > 127) ? 126 : (R));                 \
        c4 = *(const v4f*)(xpl + RR * WW + w0);                             \
        float lft = __shfl_up(c4.w, 1, 32);                                 \
        float rgt = __shfl_down(c4.x, 1, 32);                               \
        e0 = (w0 == 0)   ? c4.y : lft;   /* reflect col -1 -> 1   */        \
        e1 = (w0 == 124) ? c4.z : rgt;   /* reflect col 128 -> 126 */       \
    }

    LOADROW(r0 - 1, cP, eP0, eP1);
    LOADROW(r0,     cC, eC0, eC1);
    LOADROW(r0 + 1, cN, eN0, eN1);

#pragma unroll
    for (int i = 0; i < 4; ++i) {
        const int h = r0 + i;
        if (i < 3) { LOADROW(h + 2, cX, eX0, eX1); }   // pipelined prefetch

        const float VP[6] = {eP0, cP.x, cP.y, cP.z, cP.w, eP1};
        const float VC[6] = {eC0, cC.x, cC.y, cC.z, cC.w, eC1};
        const float VN[6] = {eN0, cN.x, cN.y, cN.z, cN.w, eN1};

        float o[4];
#pragma unroll
        for (int p = 0; p < 4; ++p) {
            float acc = 0.f;
#pragma unroll
            for (int t = 0; t < 3; ++t) {
                acc = fmaf(w9[t],     VP[p + t], acc);
                acc = fmaf(w9[3 + t], VC[p + t], acc);
                acc = fmaf(w9[6 + t], VN[p + t], acc);
            }
            o[p] = acc;
        }

        const size_t base = (size_t)plane * HWSZ + (size_t)h * WW + w0;
        v4f ov = {o[0], o[1], o[2], o[3]};
        v4f dv = {cC.x - o[0], cC.y - o[1], cC.z - o[2], cC.w - o[3]};
        __builtin_nontemporal_store(ov, (v4f*)(out + base));
        __builtin_nontemporal_store(dv, (v4f*)(out + NCHW + base));

        cP = cC; eP0 = eC0; eP1 = eC1;
        cC = cN; eC0 = eN0; eC1 = eN1;
        cN = cX; eN0 = eX0; eN1 = eX1;
    }
#undef LOADROW
}

extern "C" void kernel_launch(void* const* d_in, const int* in_sizes, int n_in,
                              void* d_out, int out_size, void* d_ws, size_t ws_size,
                              hipStream_t stream) {
    const float* x       = (const float*)d_in[0];
    const float* conv_w  = (const float*)d_in[1];
    const float* gamma   = (const float*)d_in[2];
    const float* beta    = (const float*)d_in[3];
    const float* bn_mean = (const float*)d_in[4];
    const float* bn_var  = (const float*)d_in[5];
    float* out = (float*)d_out;
    float* partial = (float*)d_ws;                // 1024 floats

    dc_mean_kernel<<<NPLANE * 2, 256, 0, stream>>>(x, partial);
    dc_conv_kernel<<<NPLANE * 4, 256, 0, stream>>>(x, partial, conv_w, gamma, beta,
                                                   bn_mean, bn_var, out);
}